// Round 1
// baseline (395.875 us; speedup 1.0000x reference)
//
#include <hip/hip_runtime.h>
#include <math.h>

// Model: RevIN -> patch embed -> 3x [LN -> S4D conv -> GELU -> GLU linear -> residual] -> head -> denorm
// B=32, L=512, CIN=32, D=128, N=64, E=3, PL=16, ST=8, PRED=96, P=64, BC=B*CIN=1024
// h global layout: (BC, D, P) row-major  => head flatten index d*64+p is contiguous.

// ---------------- RevIN: per (b,c) mean/std over L, normalize, write xt (BC, L) ----------------
__global__ __launch_bounds__(64) void revin_kernel(const float* __restrict__ x,
                                                   float* __restrict__ xt,
                                                   float* __restrict__ meanw,
                                                   float* __restrict__ stdw) {
  int bc = blockIdx.x;
  int b = bc >> 5, c = bc & 31;
  int lane = threadIdx.x;
  const float* xb = x + (size_t)b * 512 * 32 + c;
  float v[8];
  float s = 0.f, sq = 0.f;
#pragma unroll
  for (int j = 0; j < 8; ++j) {
    v[j] = xb[(size_t)(lane + 64 * j) * 32];
    s += v[j]; sq += v[j] * v[j];
  }
#pragma unroll
  for (int off = 1; off < 64; off <<= 1) {
    s += __shfl_xor(s, off);
    sq += __shfl_xor(sq, off);
  }
  float mu = s * (1.f / 512.f);
  float var = sq * (1.f / 512.f) - mu * mu;
  float sd = sqrtf(var + 1e-5f);
  float inv = 1.f / sd;
#pragma unroll
  for (int j = 0; j < 8; ++j)
    xt[(size_t)bc * 512 + lane + 64 * j] = (v[j] - mu) * inv;
  if (lane == 0) { meanw[bc] = mu; stdw[bc] = sd; }
}

// ---------------- S4D kernel K: K_all_t[e][p][h] = 2*Re(sum_n coef * exp(dtA*p)) ----------------
__global__ __launch_bounds__(64) void kcomp_kernel(const float* __restrict__ log_dt,
                                                   const float* __restrict__ arl,
                                                   const float* __restrict__ aimg,
                                                   const float* __restrict__ cre,
                                                   const float* __restrict__ cim,
                                                   float* __restrict__ K_all_t) {
  int bid = blockIdx.x;
  int e = bid >> 7, hh = bid & 127;
  int lane = threadIdx.x;
  __shared__ float cr[64], ci[64], dr[64], di[64];
  float dt = expf(log_dt[e * 128 + hh]);
  {
    int n = lane;
    size_t base = ((size_t)e * 128 + hh) * 64 + n;
    float are = -expf(arl[base]);
    float aim = aimg[base];
    float dre = are * dt, dim = aim * dt;
    float ex = expf(dre);
    float cs = cosf(dim), sn = sinf(dim);
    float er = ex * cs - 1.f, ei = ex * sn;           // exp(dtA)-1
    float invd = 1.f / (are * are + aim * aim);
    float qr = (er * are + ei * aim) * invd;          // (exp(dtA)-1)/A
    float qi = (ei * are - er * aim) * invd;
    float tr = cre[base], ti = cim[base];
    cr[n] = tr * qr - ti * qi;
    ci[n] = tr * qi + ti * qr;
    dr[n] = dre; di[n] = dim;
  }
  __syncthreads();
  int p = lane;
  float fp = (float)p;
  float sum = 0.f;
#pragma unroll 4
  for (int n = 0; n < 64; ++n) {
    float er = expf(dr[n] * fp);
    float ang = di[n] * fp;
    sum += er * (cr[n] * cosf(ang) - ci[n] * sinf(ang));
  }
  K_all_t[(size_t)e * 8192 + p * 128 + hh] = 2.f * sum;
}

// ---------------- Patch embed: h[bc][d][p] = sum_k x[p*8+k]*We[k][d] + PE[p][d] ----------------
__global__ __launch_bounds__(256) void embed_kernel(const float* __restrict__ xt,
                                                    const float* __restrict__ W_embed,
                                                    float* __restrict__ hbuf) {
  __shared__ float xts[528];
  __shared__ float Wel[2048];
  int bc = blockIdx.x, tid = threadIdx.x;
  for (int i = tid; i < 512; i += 256) xts[i] = xt[(size_t)bc * 512 + i];
  if (tid < 16) xts[512 + tid] = xt[(size_t)bc * 512 + 511];  // edge pad
  for (int i = tid; i < 2048; i += 256) Wel[i] = W_embed[i];
  __syncthreads();
  int p = tid & 63, dg = tid >> 6;
  float xr[16];
  {
    const float4* xf = (const float4*)xts;
#pragma unroll
    for (int i = 0; i < 4; ++i) {
      float4 a = xf[p * 2 + i];
      xr[4 * i] = a.x; xr[4 * i + 1] = a.y; xr[4 * i + 2] = a.z; xr[4 * i + 3] = a.w;
    }
  }
  float fp = (float)p;
#pragma unroll 4
  for (int dd = 0; dd < 32; ++dd) {
    int d = dg * 32 + dd;
    float acc = 0.f;
#pragma unroll
    for (int k = 0; k < 16; ++k) acc += xr[k] * Wel[k * 128 + d];
    float freq = expf((float)(d & ~1) * (-0.0719557841f));  // -ln(10000)/128
    float ang = fp * freq;
    float pe = (d & 1) ? cosf(ang) : sinf(ang);
    hbuf[(size_t)bc * 8192 + d * 64 + p] = acc + pe;
  }
}

// ---------------- One S4 residual layer (per-sequence block, 256 threads, 64KB LDS) ----------------
__global__ __launch_bounds__(256) void layer_kernel(float* __restrict__ hbuf,
                                                    const float* __restrict__ K_all_t,
                                                    const float* __restrict__ ln_g,
                                                    const float* __restrict__ ln_b,
                                                    const float* __restrict__ D_skip,
                                                    const float* __restrict__ W_out,
                                                    const float* __restrict__ b_out,
                                                    int e) {
  __shared__ float smem[16384];            // 64 KB
  float* zl = smem;                        // z, p-major [64][128]; later v2 buffer (swizzled float4)
  float* kt = smem + 8192;                 // K, pq-major [64][128]; later y^T [128][16 slots] swizzled
  int bc = blockIdx.x, tid = threadIdx.x;
  float* hrow = hbuf + (size_t)bc * 8192;

  for (int i = tid; i < 8192; i += 256) kt[i] = K_all_t[(size_t)e * 8192 + i];

  // ---- LayerNorm over D at each p (4 threads per p) ----
  {
    int p = tid >> 2, sub = tid & 3;
    float hv[32];
    float s = 0.f, sq = 0.f;
#pragma unroll
    for (int j = 0; j < 32; ++j) {
      int d = sub + 4 * j;
      float v = hrow[d * 64 + p];
      hv[j] = v; s += v; sq += v * v;
    }
    s += __shfl_xor(s, 1); s += __shfl_xor(s, 2);
    sq += __shfl_xor(sq, 1); sq += __shfl_xor(sq, 2);
    float mu = s * (1.f / 128.f);
    float var = sq * (1.f / 128.f) - mu * mu;
    float istd = rsqrtf(var + 1e-5f);
#pragma unroll
    for (int j = 0; j < 32; ++j) {
      int d = sub + 4 * j;
      zl[p * 128 + d] = (hv[j] - mu) * istd * ln_g[e * 128 + d] + ln_b[e * 128 + d];
    }
  }
  __syncthreads();

  // ---- causal conv (K in regs, compile-time indices) + skip + exact GELU ----
  int hh = tid & 127, pg = tid >> 7;   // thread owns channel hh, half pg of the p axis
  float y[32];
  {
    float kr[64];
#pragma unroll
    for (int i = 0; i < 64; ++i) kr[i] = kt[i * 128 + hh];
#pragma unroll
    for (int j = 0; j < 32; ++j) y[j] = 0.f;
    if (pg == 0) {
#pragma unroll
      for (int q = 0; q < 32; ++q) {
        float zv = zl[q * 128 + hh];
#pragma unroll
        for (int j = q; j < 32; ++j) y[j] += zv * kr[j - q];
      }
    } else {
#pragma unroll
      for (int q = 0; q < 64; ++q) {
        float zv = zl[q * 128 + hh];
#pragma unroll
        for (int j = (q < 32 ? 0 : q - 32); j < 32; ++j) y[j] += zv * kr[32 + j - q];
      }
    }
    float dsk = D_skip[e * 128 + hh];
#pragma unroll
    for (int j = 0; j < 32; ++j) {
      float u = zl[(pg * 32 + j) * 128 + hh];
      float t = y[j] + u * dsk;
      y[j] = 0.5f * t * (1.f + erff(t * 0.70710678f));
    }
  }
  __syncthreads();
  // write y^T into kt space: row hh, 16 float4 slots, XOR-swizzled for conflict-free reads
  {
    float4* ktf = (float4*)kt;
#pragma unroll
    for (int i = 0; i < 8; ++i) {
      int sl = pg * 8 + i;
      ktf[hh * 16 + (sl ^ (hh & 15))] =
          make_float4(y[4 * i], y[4 * i + 1], y[4 * i + 2], y[4 * i + 3]);
    }
  }
  __syncthreads();

  // ---- v[g][p] = sum_h Wout[h][g]*y[h][p] + bout[g]; GLU; residual ----
  int gt = tid >> 2, pt = tid & 3;     // thread tile: g = gt*4..+3, p = pt*16..+15
  float acc[4][16];
#pragma unroll
  for (int gi = 0; gi < 4; ++gi)
#pragma unroll
    for (int pj = 0; pj < 16; ++pj) acc[gi][pj] = 0.f;
  {
    const float4* ktf = (const float4*)kt;
    const float* wbase = W_out + (size_t)e * 32768 + gt * 4;
    for (int h2 = 0; h2 < 128; ++h2) {
      float4 w4 = *(const float4*)(wbase + h2 * 256);
      float wr[4] = {w4.x, w4.y, w4.z, w4.w};
#pragma unroll
      for (int i = 0; i < 4; ++i) {
        float4 y4 = ktf[h2 * 16 + ((pt * 4 + i) ^ (h2 & 15))];
        float yr[4] = {y4.x, y4.y, y4.z, y4.w};
#pragma unroll
        for (int gi = 0; gi < 4; ++gi)
#pragma unroll
          for (int cc = 0; cc < 4; ++cc)
            acc[gi][4 * i + cc] += wr[gi] * yr[cc];
      }
    }
  }
#pragma unroll
  for (int gi = 0; gi < 4; ++gi) {
    float bo = b_out[e * 256 + gt * 4 + gi];
#pragma unroll
    for (int pj = 0; pj < 16; ++pj) acc[gi][pj] += bo;
  }
  float4* v2l = (float4*)zl;
  if (tid >= 128) {                     // these threads hold v2 (g in 128..255)
#pragma unroll
    for (int gi = 0; gi < 4; ++gi) {
      int g2 = (gt - 32) * 4 + gi;
#pragma unroll
      for (int i = 0; i < 4; ++i)
        v2l[g2 * 16 + ((pt * 4 + i) ^ (g2 & 15))] =
            make_float4(acc[gi][4 * i], acc[gi][4 * i + 1], acc[gi][4 * i + 2], acc[gi][4 * i + 3]);
    }
  }
  __syncthreads();
  if (tid < 128) {                      // v1 holders: GLU + residual + store
#pragma unroll
    for (int gi = 0; gi < 4; ++gi) {
      int g = gt * 4 + gi;
#pragma unroll
      for (int i = 0; i < 4; ++i) {
        float4 v2 = v2l[g * 16 + ((pt * 4 + i) ^ (g & 15))];
        int p0 = pt * 16 + 4 * i;
        float4 hold = *(float4*)(hrow + g * 64 + p0);
        float4 r;
        r.x = acc[gi][4 * i + 0] * (1.f / (1.f + expf(-v2.x))) + hold.x;
        r.y = acc[gi][4 * i + 1] * (1.f / (1.f + expf(-v2.y))) + hold.y;
        r.z = acc[gi][4 * i + 2] * (1.f / (1.f + expf(-v2.z))) + hold.z;
        r.w = acc[gi][4 * i + 3] * (1.f / (1.f + expf(-v2.w))) + hold.w;
        *(float4*)(hrow + g * 64 + p0) = r;
      }
    }
  }
}

// ---------------- Head: partial GEMM over f-slice. grid = (b, fs) = 32*8, 192 thr ----------------
__global__ __launch_bounds__(192) void head_kernel(const float* __restrict__ hbuf,
                                                   const float* __restrict__ W_head,
                                                   float* __restrict__ part) {
  __shared__ float smem[16384];
  float* Wl = smem;          // [128][96]
  float* hlt = smem + 12288; // [128][32], float4-slot swizzled
  int bid = blockIdx.x;
  int b = bid >> 3, fs = bid & 7;
  int tid = threadIdx.x;
  int tt = tid >> 3, ct = tid & 7;  // t tile 0..23, c tile 0..7
  float acc[4][4];
#pragma unroll
  for (int i = 0; i < 4; ++i)
#pragma unroll
    for (int j = 0; j < 4; ++j) acc[i][j] = 0.f;

  for (int ch = 0; ch < 8; ++ch) {
    int f0 = fs * 1024 + ch * 128;
    __syncthreads();
    for (int i = tid; i < 12288; i += 192) Wl[i] = W_head[(size_t)f0 * 96 + i];
    for (int i = tid; i < 4096; i += 192) {
      int f = i & 127, c = i >> 7;
      hlt[f * 32 + ((((c >> 2) ^ (f & 7)) << 2) | (c & 3))] =
          hbuf[((size_t)b * 32 + c) * 8192 + f0 + f];
    }
    __syncthreads();
    const float4* hf = (const float4*)hlt;
    for (int f = 0; f < 128; ++f) {
      float4 w4 = *(const float4*)(Wl + f * 96 + tt * 4);
      float4 h4 = hf[f * 8 + (ct ^ (f & 7))];
      float wr[4] = {w4.x, w4.y, w4.z, w4.w};
      float hr[4] = {h4.x, h4.y, h4.z, h4.w};
#pragma unroll
      for (int ti = 0; ti < 4; ++ti)
#pragma unroll
        for (int ci = 0; ci < 4; ++ci) acc[ti][ci] += wr[ti] * hr[ci];
    }
  }
#pragma unroll
  for (int ci = 0; ci < 4; ++ci) {
    int c = ct * 4 + ci;
#pragma unroll
    for (int ti = 0; ti < 4; ++ti) {
      int t = tt * 4 + ti;
      part[(((size_t)fs * 32 + b) * 32 + c) * 96 + t] = acc[ti][ci];
    }
  }
}

// ---------------- Reduce partials + bias + RevIN denorm -> out (B, PRED, C) ----------------
__global__ __launch_bounds__(256) void reduce_kernel(const float* __restrict__ part,
                                                     const float* __restrict__ b_head,
                                                     const float* __restrict__ meanw,
                                                     const float* __restrict__ stdw,
                                                     float* __restrict__ out) {
  int o = blockIdx.x * 256 + threadIdx.x;  // 98304 total
  int c = o & 31;
  int bt = o >> 5;
  int t = bt % 96;
  int b = bt / 96;
  float s = b_head[t];
#pragma unroll
  for (int fs = 0; fs < 8; ++fs)
    s += part[(((size_t)fs * 32 + b) * 32 + c) * 96 + t];
  out[o] = s * stdw[b * 32 + c] + meanw[b * 32 + c];
}

extern "C" void kernel_launch(void* const* d_in, const int* in_sizes, int n_in,
                              void* d_out, int out_size, void* d_ws, size_t ws_size,
                              hipStream_t stream) {
  const float* x_enc  = (const float*)d_in[0];
  const float* W_embed = (const float*)d_in[4];
  const float* ln_g   = (const float*)d_in[5];
  const float* ln_b   = (const float*)d_in[6];
  const float* log_dt = (const float*)d_in[7];
  const float* arl    = (const float*)d_in[8];
  const float* aimg   = (const float*)d_in[9];
  const float* cre    = (const float*)d_in[10];
  const float* cim    = (const float*)d_in[11];
  const float* dskip  = (const float*)d_in[12];
  const float* wout   = (const float*)d_in[13];
  const float* bout   = (const float*)d_in[14];
  const float* whead  = (const float*)d_in[15];
  const float* bhead  = (const float*)d_in[16];

  float* ws    = (float*)d_ws;
  float* xt    = ws;                    // 1024*512
  float* meanw = xt + 524288;           // 1024
  float* stdw  = meanw + 1024;          // 1024
  float* kall  = stdw + 1024;           // 3*64*128
  float* hbuf  = kall + 24576;          // 1024*8192
  float* partw = hbuf + 8388608;        // 8*32*32*96

  float* out = (float*)d_out;

  revin_kernel<<<1024, 64, 0, stream>>>(x_enc, xt, meanw, stdw);
  kcomp_kernel<<<384, 64, 0, stream>>>(log_dt, arl, aimg, cre, cim, kall);
  embed_kernel<<<1024, 256, 0, stream>>>(xt, W_embed, hbuf);
  for (int e = 0; e < 3; ++e)
    layer_kernel<<<1024, 256, 0, stream>>>(hbuf, kall, ln_g, ln_b, dskip, wout, bout, e);
  head_kernel<<<256, 192, 0, stream>>>(hbuf, whead, partw);
  reduce_kernel<<<384, 256, 0, stream>>>(partw, bhead, meanw, stdw, out);
}

// Round 2
// 196.369 us; speedup vs baseline: 2.0160x; 2.0160x over previous
//
#include <hip/hip_runtime.h>
#include <math.h>

// B=32, L=512, CIN=32, D=128, N=64, E=3, PL=16, ST=8, PRED=96, P=64, BC=1024
// h layout: (BC, D, P) row-major. Matmuls in bf16 MFMA (fp32 accum); residual/LN/conv/GELU fp32.

typedef __attribute__((ext_vector_type(8))) short bf16x8;
typedef __attribute__((ext_vector_type(4))) float f32x4;

__device__ __forceinline__ ushort f2bf(float f) {
  uint u = __float_as_uint(f);
  return (ushort)((u + 0x7FFFu + ((u >> 16) & 1u)) >> 16);
}

// z-tile swizzle: kills 16-way bank conflict on LN transposed write
#define ZIDX(p, d) ((p) * 128 + ((d) ^ (((p) & 7) << 2)))

// ---------------- RevIN ----------------
__global__ __launch_bounds__(64) void revin_kernel(const float* __restrict__ x,
                                                   float* __restrict__ xt,
                                                   float* __restrict__ meanw,
                                                   float* __restrict__ stdw) {
  int bc = blockIdx.x;
  int b = bc >> 5, c = bc & 31;
  int lane = threadIdx.x;
  const float* xb = x + (size_t)b * 512 * 32 + c;
  float v[8];
  float s = 0.f, sq = 0.f;
#pragma unroll
  for (int j = 0; j < 8; ++j) {
    v[j] = xb[(size_t)(lane + 64 * j) * 32];
    s += v[j]; sq += v[j] * v[j];
  }
#pragma unroll
  for (int off = 1; off < 64; off <<= 1) {
    s += __shfl_xor(s, off);
    sq += __shfl_xor(sq, off);
  }
  float mu = s * (1.f / 512.f);
  float var = sq * (1.f / 512.f) - mu * mu;
  float sd = sqrtf(var + 1e-5f);
  float inv = 1.f / sd;
#pragma unroll
  for (int j = 0; j < 8; ++j)
    xt[(size_t)bc * 512 + lane + 64 * j] = (v[j] - mu) * inv;
  if (lane == 0) { meanw[bc] = mu; stdw[bc] = sd; }
}

// ---------------- S4D kernel K[e][p][h] ----------------
__global__ __launch_bounds__(64) void kcomp_kernel(const float* __restrict__ log_dt,
                                                   const float* __restrict__ arl,
                                                   const float* __restrict__ aimg,
                                                   const float* __restrict__ cre,
                                                   const float* __restrict__ cim,
                                                   float* __restrict__ K_all_t) {
  int bid = blockIdx.x;
  int e = bid >> 7, hh = bid & 127;
  int lane = threadIdx.x;
  __shared__ float cr[64], ci[64], dr[64], di[64];
  float dt = expf(log_dt[e * 128 + hh]);
  {
    int n = lane;
    size_t base = ((size_t)e * 128 + hh) * 64 + n;
    float are = -expf(arl[base]);
    float aim = aimg[base];
    float dre = are * dt, dim = aim * dt;
    float ex = expf(dre);
    float cs = cosf(dim), sn = sinf(dim);
    float er = ex * cs - 1.f, ei = ex * sn;
    float invd = 1.f / (are * are + aim * aim);
    float qr = (er * are + ei * aim) * invd;
    float qi = (ei * are - er * aim) * invd;
    float tr = cre[base], ti = cim[base];
    cr[n] = tr * qr - ti * qi;
    ci[n] = tr * qi + ti * qr;
    dr[n] = dre; di[n] = dim;
  }
  __syncthreads();
  int p = lane;
  float fp = (float)p;
  float sum = 0.f;
#pragma unroll 4
  for (int n = 0; n < 64; ++n) {
    float er = expf(dr[n] * fp);
    float ang = di[n] * fp;
    sum += er * (cr[n] * cosf(ang) - ci[n] * sinf(ang));
  }
  K_all_t[(size_t)e * 8192 + p * 128 + hh] = 2.f * sum;
}

// ---------------- Prep: bf16 W_out^T, bf16 W_head^T, PE table ----------------
__global__ __launch_bounds__(256) void prep_kernel(const float* __restrict__ W_out,
                                                   const float* __restrict__ W_head,
                                                   ushort* __restrict__ wt,
                                                   ushort* __restrict__ wth,
                                                   float* __restrict__ pe) {
  __shared__ ushort lbuf[12800];
  int bid = blockIdx.x, tid = threadIdx.x;
  if (bid < 64) {                 // W_head^T tile: f0 = bid*128, wth[t][f] (96 x 8192)
    int f0 = bid << 7;
    for (int i = tid; i < 12288; i += 256) {
      int f = i / 96, t = i - f * 96;
      lbuf[f * 100 + t] = f2bf(W_head[(size_t)(f0 + f) * 96 + t]);
    }
    __syncthreads();
    for (int i = tid; i < 12288; i += 256) {
      int t = i >> 7, f = i & 127;
      wth[(size_t)t * 8192 + f0 + f] = lbuf[f * 100 + t];
    }
  } else if (bid < 67) {          // W_out^T per e: wt[e][g][h] (256 x 128)
    int e = bid - 64;
    for (int h0 = 0; h0 < 128; h0 += 32) {
      __syncthreads();
      for (int i = tid; i < 8192; i += 256) {
        int hh = i >> 8, g = i & 255;
        lbuf[hh * 260 + g] = f2bf(W_out[e * 32768 + (h0 + hh) * 256 + g]);
      }
      __syncthreads();
      for (int i = tid; i < 8192; i += 256) {
        int g = i >> 5, hh = i & 31;
        wt[(size_t)(e * 256 + g) * 128 + h0 + hh] = lbuf[hh * 260 + g];
      }
    }
  } else {                        // PE table
    int i = (bid - 67) * 256 + tid;
    int p = i >> 7, d = i & 127;
    float freq = expf((float)(d & ~1) * (-0.0719557841f));  // -ln(10000)/128
    float ang = (float)p * freq;
    pe[i] = (d & 1) ? cosf(ang) : sinf(ang);
  }
}

// ---------------- Patch embed ----------------
__global__ __launch_bounds__(256) void embed_kernel(const float* __restrict__ xt,
                                                    const float* __restrict__ W_embed,
                                                    const float* __restrict__ pe,
                                                    float* __restrict__ hbuf) {
  __shared__ float xts[528];
  __shared__ float Wel[2048];
  int bc = blockIdx.x, tid = threadIdx.x;
  for (int i = tid; i < 512; i += 256) xts[i] = xt[(size_t)bc * 512 + i];
  if (tid < 16) xts[512 + tid] = xt[(size_t)bc * 512 + 511];
  for (int i = tid; i < 2048; i += 256) Wel[i] = W_embed[i];
  __syncthreads();
  int p = tid & 63, dg = tid >> 6;
  float xr[16];
  {
    const float4* xf = (const float4*)xts;
#pragma unroll
    for (int i = 0; i < 4; ++i) {
      float4 a = xf[p * 2 + i];
      xr[4 * i] = a.x; xr[4 * i + 1] = a.y; xr[4 * i + 2] = a.z; xr[4 * i + 3] = a.w;
    }
  }
#pragma unroll 4
  for (int dd = 0; dd < 32; ++dd) {
    int d = dg * 32 + dd;
    float acc = 0.f;
#pragma unroll
    for (int k = 0; k < 16; ++k) acc += xr[k] * Wel[k * 128 + d];
    hbuf[(size_t)bc * 8192 + d * 64 + p] = acc + pe[p * 128 + d];
  }
}

// ---------------- S4 residual layer: LN + conv + GELU fp32, GLU linear in MFMA bf16 ----------------
__global__ __launch_bounds__(256) void layer_kernel(float* __restrict__ hbuf,
                                                    const float* __restrict__ K_all_t,
                                                    const float* __restrict__ ln_g,
                                                    const float* __restrict__ ln_b,
                                                    const float* __restrict__ D_skip,
                                                    const ushort* __restrict__ wt,
                                                    const float* __restrict__ b_out,
                                                    int e) {
  __shared__ float zl[8192];      // z, swizzled [64][128]
  __shared__ ushort ys[8192];     // y^T bf16, [64 p][128 h], 16B-slot XOR swizzle
  int bc = blockIdx.x, tid = threadIdx.x;
  float* hrow = hbuf + (size_t)bc * 8192;
  int hh = tid & 127, pg = tid >> 7;

  // K into registers (L2-resident), issue early
  float kr[64];
  {
    const float* kb = K_all_t + e * 8192 + hh;
#pragma unroll
    for (int i = 0; i < 64; ++i) kr[i] = kb[i * 128];
  }

  // ---- LayerNorm over D at each p (4 threads per p) ----
  {
    int p = tid >> 2, sub = tid & 3;
    float hv[32];
    float s = 0.f, sq = 0.f;
#pragma unroll
    for (int j = 0; j < 32; ++j) {
      int d = sub + 4 * j;
      float v = hrow[d * 64 + p];
      hv[j] = v; s += v; sq += v * v;
    }
    s += __shfl_xor(s, 1); s += __shfl_xor(s, 2);
    sq += __shfl_xor(sq, 1); sq += __shfl_xor(sq, 2);
    float mu = s * (1.f / 128.f);
    float var = sq * (1.f / 128.f) - mu * mu;
    float istd = rsqrtf(var + 1e-5f);
#pragma unroll
    for (int j = 0; j < 32; ++j) {
      int d = sub + 4 * j;
      zl[ZIDX(p, d)] = (hv[j] - mu) * istd * ln_g[e * 128 + d] + ln_b[e * 128 + d];
    }
  }
  __syncthreads();

  // ---- causal conv, balanced interleaved p-split (thread owns p = 2j+pg) ----
  float y[32];
#pragma unroll
  for (int j = 0; j < 32; ++j) y[j] = 0.f;
  if (pg == 0) {
#pragma unroll
    for (int q = 0; q < 63; ++q) {
      float zv = zl[ZIDX(q, hh)];
#pragma unroll
      for (int j = (q + 1) >> 1; j < 32; ++j) y[j] += zv * kr[2 * j - q];
    }
  } else {
#pragma unroll
    for (int q = 0; q < 64; ++q) {
      float zv = zl[ZIDX(q, hh)];
#pragma unroll
      for (int j = q >> 1; j < 32; ++j) y[j] += zv * kr[2 * j + 1 - q];
    }
  }
  // skip + exact GELU + bf16 -> ys (swizzled)
  {
    float dsk = D_skip[e * 128 + hh];
#pragma unroll
    for (int j = 0; j < 32; ++j) {
      int p = 2 * j + pg;
      float u = zl[ZIDX(p, hh)];
      float t = y[j] + u * dsk;
      float g = 0.5f * t * (1.f + erff(t * 0.70710678f));
      int slot = hh >> 3;
      ys[p * 128 + ((slot ^ (p & 15)) << 3) + (hh & 7)] = f2bf(g);
    }
  }
  __syncthreads();

  // ---- MFMA GLU linear: v[g][p] = sum_h Wt[g][h] * y^T[p][h] ----
  int w = tid >> 6, l = tid & 63;
  int lr = l & 15, lk = l >> 4;
  f32x4 acc[4][4];
#pragma unroll
  for (int m = 0; m < 4; ++m)
#pragma unroll
    for (int n = 0; n < 4; ++n) acc[m][n] = (f32x4){0.f, 0.f, 0.f, 0.f};
  const ushort* wbase = wt + (size_t)e * 32768;
#pragma unroll
  for (int ks = 0; ks < 4; ++ks) {
    int kofs = ks * 32 + lk * 8;
    bf16x8 a[4], bfr[4];
#pragma unroll
    for (int mf = 0; mf < 4; ++mf) {
      int gm = (mf < 2) ? (w * 32 + mf * 16) : (128 + w * 32 + (mf - 2) * 16);
      a[mf] = *(const bf16x8*)(wbase + (size_t)(gm + lr) * 128 + kofs);
    }
#pragma unroll
    for (int nf = 0; nf < 4; ++nf) {
      int p = nf * 16 + lr;
      int slot = (ks * 4 + lk) ^ (p & 15);
      bfr[nf] = *(const bf16x8*)(ys + p * 128 + slot * 8);
    }
#pragma unroll
    for (int mf = 0; mf < 4; ++mf)
#pragma unroll
      for (int nf = 0; nf < 4; ++nf)
        acc[mf][nf] = __builtin_amdgcn_mfma_f32_16x16x32_bf16(a[mf], bfr[nf], acc[mf][nf], 0, 0, 0);
  }

  // ---- epilogue: bias + GLU + residual (wave w owns v1 g in [w*32,+32), v2 at g+128) ----
#pragma unroll
  for (int mf = 0; mf < 2; ++mf)
#pragma unroll
    for (int nf = 0; nf < 4; ++nf)
#pragma unroll
      for (int r = 0; r < 4; ++r) {
        int g = w * 32 + mf * 16 + lk * 4 + r;
        int p = nf * 16 + lr;
        float v1 = acc[mf][nf][r] + b_out[e * 256 + g];
        float v2 = acc[mf + 2][nf][r] + b_out[e * 256 + 128 + g];
        float sig = 1.f / (1.f + expf(-v2));
        int idx = g * 64 + p;
        hrow[idx] = v1 * sig + hrow[idx];
      }
}

// ---------------- Head: MFMA GEMM (1024 x 96 x 8192), grid (b, kc) = 32x8 ----------------
__global__ __launch_bounds__(256) void head_kernel(const float* __restrict__ hbuf,
                                                   const ushort* __restrict__ wth,
                                                   float* __restrict__ part) {
  __shared__ float sred[12288];   // [4 waves][32 c][96 t]
  int bid = blockIdx.x;
  int b = bid >> 3, kc = bid & 7;
  int tid = threadIdx.x, w = tid >> 6, l = tid & 63;
  int lr = l & 15, lk = l >> 4;
  int kwbase = kc * 1024 + w * 256;
  f32x4 acc[2][6];
#pragma unroll
  for (int m = 0; m < 2; ++m)
#pragma unroll
    for (int n = 0; n < 6; ++n) acc[m][n] = (f32x4){0.f, 0.f, 0.f, 0.f};
#pragma unroll 2
  for (int ks = 0; ks < 8; ++ks) {
    int kb = kwbase + ks * 32 + lk * 8;
    bf16x8 a[2];
#pragma unroll
    for (int mf = 0; mf < 2; ++mf) {
      const float* src = hbuf + (size_t)(b * 32 + mf * 16 + lr) * 8192 + kb;
      float4 x0 = *(const float4*)src;
      float4 x1 = *(const float4*)(src + 4);
      bf16x8 t;
      t[0] = (short)f2bf(x0.x); t[1] = (short)f2bf(x0.y);
      t[2] = (short)f2bf(x0.z); t[3] = (short)f2bf(x0.w);
      t[4] = (short)f2bf(x1.x); t[5] = (short)f2bf(x1.y);
      t[6] = (short)f2bf(x1.z); t[7] = (short)f2bf(x1.w);
      a[mf] = t;
    }
#pragma unroll
    for (int nf = 0; nf < 6; ++nf) {
      bf16x8 bb = *(const bf16x8*)(wth + (size_t)(nf * 16 + lr) * 8192 + kb);
#pragma unroll
      for (int mf = 0; mf < 2; ++mf)
        acc[mf][nf] = __builtin_amdgcn_mfma_f32_16x16x32_bf16(a[mf], bb, acc[mf][nf], 0, 0, 0);
    }
  }
#pragma unroll
  for (int mf = 0; mf < 2; ++mf)
#pragma unroll
    for (int nf = 0; nf < 6; ++nf)
#pragma unroll
      for (int r = 0; r < 4; ++r) {
        int c = mf * 16 + lk * 4 + r;
        int t = nf * 16 + lr;
        sred[w * 3072 + c * 96 + t] = acc[mf][nf][r];
      }
  __syncthreads();
  for (int i = tid; i < 3072; i += 256) {
    float s = sred[i] + sred[3072 + i] + sred[6144 + i] + sred[9216 + i];
    part[(size_t)(kc * 32 + b) * 3072 + i] = s;
  }
}

// ---------------- Reduce partials + bias + denorm ----------------
__global__ __launch_bounds__(256) void reduce_kernel(const float* __restrict__ part,
                                                     const float* __restrict__ b_head,
                                                     const float* __restrict__ meanw,
                                                     const float* __restrict__ stdw,
                                                     float* __restrict__ out) {
  int o = blockIdx.x * 256 + threadIdx.x;
  int c = o & 31;
  int bt = o >> 5;
  int t = bt % 96;
  int b = bt / 96;
  float s = b_head[t];
#pragma unroll
  for (int fs = 0; fs < 8; ++fs)
    s += part[(((size_t)fs * 32 + b) * 32 + c) * 96 + t];
  out[o] = s * stdw[b * 32 + c] + meanw[b * 32 + c];
}

extern "C" void kernel_launch(void* const* d_in, const int* in_sizes, int n_in,
                              void* d_out, int out_size, void* d_ws, size_t ws_size,
                              hipStream_t stream) {
  const float* x_enc   = (const float*)d_in[0];
  const float* W_embed = (const float*)d_in[4];
  const float* ln_g    = (const float*)d_in[5];
  const float* ln_b    = (const float*)d_in[6];
  const float* log_dt  = (const float*)d_in[7];
  const float* arl     = (const float*)d_in[8];
  const float* aimg    = (const float*)d_in[9];
  const float* cre     = (const float*)d_in[10];
  const float* cim     = (const float*)d_in[11];
  const float* dskip   = (const float*)d_in[12];
  const float* wout    = (const float*)d_in[13];
  const float* bout    = (const float*)d_in[14];
  const float* whead   = (const float*)d_in[15];
  const float* bhead   = (const float*)d_in[16];

  float* ws    = (float*)d_ws;
  float* meanw = ws;                      // 1024
  float* stdw  = meanw + 1024;            // 1024
  float* kall  = stdw + 1024;             // 24576
  ushort* wt   = (ushort*)(kall + 24576); // 98304 ushorts -> 49152 floats
  ushort* wth  = (ushort*)(kall + 24576 + 49152);  // 786432 ushorts -> 393216 floats
  float* pe    = kall + 24576 + 49152 + 393216;    // 8192
  float* hbuf  = pe + 8192;               // 8388608
  float* xt    = hbuf + 8388608;          // union: xt (524288) / part (786432)
  float* partw = xt;

  float* out = (float*)d_out;

  prep_kernel<<<99, 256, 0, stream>>>(wout, whead, wt, wth, pe);
  revin_kernel<<<1024, 64, 0, stream>>>(x_enc, xt, meanw, stdw);
  kcomp_kernel<<<384, 64, 0, stream>>>(log_dt, arl, aimg, cre, cim, kall);
  embed_kernel<<<1024, 256, 0, stream>>>(xt, W_embed, pe, hbuf);
  for (int e = 0; e < 3; ++e)
    layer_kernel<<<1024, 256, 0, stream>>>(hbuf, kall, ln_g, ln_b, dskip, wt, bout, e);
  head_kernel<<<256, 256, 0, stream>>>(hbuf, wth, partw);
  reduce_kernel<<<384, 256, 0, stream>>>(partw, bhead, meanw, stdw, out);
}